// Round 2
// 309.036 us; speedup vs baseline: 1.0589x; 1.0589x over previous
//
#include <hip/hip_runtime.h>
#include <stdint.h>

#define NN 100000
#define FF 128
#define NB 391              // ceil(NN/256) buckets of 256 nodes

typedef __bf16 bf16x8 __attribute__((ext_vector_type(8)));
typedef float f32x4 __attribute__((ext_vector_type(4)));

__device__ __forceinline__ unsigned short f2bf(float f) {
    unsigned int u = __float_as_uint(f);
    u += 0x7FFF + ((u >> 16) & 1);          // round-to-nearest-even
    return (unsigned short)(u >> 16);
}
__device__ __forceinline__ float bf2f(unsigned short b) {
    return __uint_as_float(((unsigned int)b) << 16);
}

__device__ __forceinline__ int edge_at(const void* ei, int idx, int is64) {
    if (is64) return (int)((const long long*)ei)[idx];
    return ((const int*)ei)[idx];
}

// ---------- init: zero bucket counters + edge dtype detect ----------
__global__ void init_kernel(const unsigned int* ei, int* flag, int* bcnt) {
    __shared__ int any;
    int t = threadIdx.x;
    if (t == 0) any = 0;
    for (int i = t; i < NB; i += 512) bcnt[i] = 0;
    __syncthreads();
    unsigned int v = ei[2 * t + 1];
    if (v != 0u) atomicOr(&any, 1);
    __syncthreads();
    if (t == 0) *flag = (any ? 0 : 1);  // 1 => int64
}

// ---------- fused: bucket histogram (blocks 0-255) + prep (blocks 256+) ----------
__global__ void bcount_prep_kernel(const void* ei, const int* flag, int* bcnt, int E,
                                   const float* __restrict__ x, unsigned short* __restrict__ xb,
                                   const float* Wl0, const float* Wr0,
                                   const float* Wl1, const float* Wr1,
                                   const float* Wl2, const float* Wr2,
                                   unsigned short* __restrict__ whi) {
    if (blockIdx.x < 256) {
        __shared__ int h[NB];
        for (int i = threadIdx.x; i < NB; i += 256) h[i] = 0;
        __syncthreads();
        int is64 = *flag;
        int stride = 256 * 256;
        for (int e = blockIdx.x * 256 + threadIdx.x; e < E; e += stride)
            atomicAdd(&h[edge_at(ei, E + e, is64) >> 8], 1);
        __syncthreads();
        for (int i = threadIdx.x; i < NB; i += 256) {
            int v = h[i];
            if (v) atomicAdd(&bcnt[i], v);
        }
    } else {
        int gid = (blockIdx.x - 256) * 256 + threadIdx.x;
        int gstride = (gridDim.x - 256) * 256;
        const int PC = NN * FF / 8;
        for (int i = gid; i < PC; i += gstride) {
            float4 a = ((const float4*)x)[i * 2];
            float4 b = ((const float4*)x)[i * 2 + 1];
            ushort4 p0 = make_ushort4(f2bf(a.x), f2bf(a.y), f2bf(a.z), f2bf(a.w));
            ushort4 p1 = make_ushort4(f2bf(b.x), f2bf(b.y), f2bf(b.z), f2bf(b.w));
            ((ushort4*)xb)[i * 2] = p0;
            ((ushort4*)xb)[i * 2 + 1] = p1;
        }
        const int WT = 3 * 256 * FF;
        for (int i = gid; i < WT; i += gstride) {
            int l = i >> 15;                 // / (256*128)
            int rem = i & 32767;
            int n = rem >> 7;
            int k = rem & 127;
            const float* Wl = l == 0 ? Wl0 : (l == 1 ? Wl1 : Wl2);
            const float* Wr = l == 0 ? Wr0 : (l == 1 ? Wr1 : Wr2);
            float v = (n < FF) ? Wl[k * FF + n] : Wr[k * FF + (n - FF)];
            whi[i] = f2bf(v);
        }
    }
}

__global__ void bscan_kernel(const int* bcnt, int* bbase, int* bcursor,
                             int* rowptr, int E) {
    __shared__ int s[512];
    int t = threadIdx.x;
    int v = (t < NB) ? bcnt[t] : 0;
    s[t] = v;
    __syncthreads();
    for (int off = 1; off < 512; off <<= 1) {
        int u = (t >= off) ? s[t - off] : 0;
        __syncthreads();
        s[t] += u;
        __syncthreads();
    }
    if (t <= NB) {
        int excl = (t == 0) ? 0 : s[t - 1];
        bbase[t] = excl;                 // bbase[NB] == E
        if (t < NB) bcursor[t] = excl;
    }
    if (t == 0) rowptr[NN] = E;
}

// each block reserves per-bucket runs, writes packed (src<<8 | dstLocal)
__global__ void bscatter_kernel(const void* ei, const int* flag, int* bcursor,
                                unsigned int* packed, int E, int CH) {
    __shared__ int cnt[NB];
    __shared__ int base[NB];
    int t = threadIdx.x;
    for (int i = t; i < NB; i += 256) cnt[i] = 0;
    __syncthreads();
    int is64 = *flag;
    int beg = blockIdx.x * CH;
    int end = min(E, beg + CH);
    for (int e = beg + t; e < end; e += 256)
        atomicAdd(&cnt[edge_at(ei, E + e, is64) >> 8], 1);
    __syncthreads();
    for (int i = t; i < NB; i += 256) {
        int c = cnt[i];
        base[i] = c ? atomicAdd(&bcursor[i], c) : 0;
    }
    __syncthreads();
    for (int i = t; i < NB; i += 256) cnt[i] = 0;
    __syncthreads();
    for (int e = beg + t; e < end; e += 256) {
        int sV = edge_at(ei, e, is64);
        int d  = edge_at(ei, E + e, is64);
        int b = d >> 8;
        int pos = base[b] + atomicAdd(&cnt[b], 1);
        packed[pos] = ((unsigned int)sV << 8) | (unsigned int)(d & 255);
    }
}

// one block per bucket: local count+scan -> rowptr, local cursor scatter -> col
__global__ void bfill_kernel(const unsigned int* __restrict__ packed,
                             const int* __restrict__ bbase,
                             int* __restrict__ rowptr, int* __restrict__ col) {
    __shared__ int cnt[256];
    __shared__ int scn[256];
    __shared__ int exc[256];
    int t = threadIdx.x;
    int b = blockIdx.x;
    int ebeg = bbase[b], eend = bbase[b + 1];
    cnt[t] = 0;
    __syncthreads();
    for (int e = ebeg + t; e < eend; e += 256)
        atomicAdd(&cnt[packed[e] & 255], 1);
    __syncthreads();
    int v = cnt[t];
    scn[t] = v;
    __syncthreads();
    for (int off = 1; off < 256; off <<= 1) {
        int u = (t >= off) ? scn[t - off] : 0;
        __syncthreads();
        scn[t] += u;
        __syncthreads();
    }
    int excl = scn[t] - v;
    exc[t] = excl;
    int node = b * 256 + t;
    if (node < NN) rowptr[node] = ebeg + excl;
    cnt[t] = 0;                           // reuse as cursor
    __syncthreads();
    for (int e = ebeg + t; e < eend; e += 256) {
        unsigned int p = packed[e];
        int l = p & 255;
        int pos = ebeg + exc[l] + atomicAdd(&cnt[l], 1);
        col[pos] = (int)(p >> 8);
    }
}

// ---------- aggregation: m_i = mean_{j in N(i)} h_j  (bf16 in, bf16 out) ----------
// One wave per dst. 64 lanes x 4B = one full 256B feature row per load instr.
// All addressing is scalar: beg/end/col are wave-uniform; col fetched as a
// 64-wide batch once per wave, per-edge index pulled via v_readlane (SGPR),
// row base = SALU math, per-lane voffset (lane*4) is loop-invariant.
// Depth-4 software pipeline keeps 4 row loads in flight.
__device__ __forceinline__ unsigned int rowld(const unsigned short* __restrict__ h,
                                              int c, int lbyte) {
    return *(const unsigned int*)((const char*)h + ((size_t)(unsigned)c << 8) + lbyte);
}

__global__ void aggregate_kernel(const unsigned short* __restrict__ h,
                                 const int* __restrict__ rowptr,
                                 const int* __restrict__ col,
                                 unsigned short* __restrict__ m) {
    int gw = (int)((blockIdx.x * blockDim.x + threadIdx.x) >> 6);
    gw = __builtin_amdgcn_readfirstlane(gw);
    if (gw >= NN) return;
    const int lane = (int)(threadIdx.x & 63);
    const int lbyte = lane * 4;
    int beg = __builtin_amdgcn_readfirstlane(rowptr[gw]);
    int end = __builtin_amdgcn_readfirstlane(rowptr[gw + 1]);
    int deg = end - beg;
    float a0 = 0.f, a1 = 0.f;

    int done = 0;
    while (done < deg) {
        int batch = min(deg - done, 64);
        int colv = 0;
        if (lane < batch) colv = col[beg + done + lane];
        unsigned int u0 = 0, u1 = 0, u2 = 0, u3 = 0;
        u0 = rowld(h, __builtin_amdgcn_readlane(colv, 0), lbyte);
        if (batch > 1) u1 = rowld(h, __builtin_amdgcn_readlane(colv, 1), lbyte);
        if (batch > 2) u2 = rowld(h, __builtin_amdgcn_readlane(colv, 2), lbyte);
        if (batch > 3) u3 = rowld(h, __builtin_amdgcn_readlane(colv, 3), lbyte);
        for (int i = 0; i < batch; i += 4) {
            unsigned int n0 = 0, n1 = 0, n2 = 0, n3 = 0;
            if (i + 4 < batch) n0 = rowld(h, __builtin_amdgcn_readlane(colv, i + 4), lbyte);
            if (i + 5 < batch) n1 = rowld(h, __builtin_amdgcn_readlane(colv, i + 5), lbyte);
            if (i + 6 < batch) n2 = rowld(h, __builtin_amdgcn_readlane(colv, i + 6), lbyte);
            if (i + 7 < batch) n3 = rowld(h, __builtin_amdgcn_readlane(colv, i + 7), lbyte);
            a0 += __uint_as_float(u0 << 16);
            a1 += __uint_as_float(u0 & 0xffff0000u);
            a0 += __uint_as_float(u1 << 16);
            a1 += __uint_as_float(u1 & 0xffff0000u);
            a0 += __uint_as_float(u2 << 16);
            a1 += __uint_as_float(u2 & 0xffff0000u);
            a0 += __uint_as_float(u3 << 16);
            a1 += __uint_as_float(u3 & 0xffff0000u);
            u0 = n0; u1 = n1; u2 = n2; u3 = n3;
        }
        done += batch;
    }

    float r = deg > 0 ? 1.f / (float)deg : 0.f;
    unsigned int p = (unsigned int)f2bf(a0 * r) | ((unsigned int)f2bf(a1 * r) << 16);
    *(unsigned int*)((char*)m + ((size_t)gw << 8) + lbyte) = p;
}

// ---------- GEMM: out = m@Wl + h@Wr + bl  (bf16 W direct from L2) ----------
// 256 threads, M-tile 64 x N 128, 4 waves n-split (wid*32), acc[4][2].
// Only M/H staged in LDS (10 KB); W fragments loaded per-lane from global (L2-hot).
// Swapped mfma -> C^T frags -> swizzled LDS C-tile (16 KB) -> coalesced stores.
// WMODE 0: bf16 + relu. WMODE 1: fp32, no relu (two 32-row rounds).
template <int WMODE>
__global__ __launch_bounds__(256, 6) void gemm_mfma_kernel(
        const unsigned short* __restrict__ mb,    // [NN][128] bf16 mean
        const unsigned short* __restrict__ hb,    // [NN][128] bf16 root
        const unsigned short* __restrict__ w2,    // [256][128]: rows 0-127 Wl, 128-255 Wr
        const float* __restrict__ bl,
        void* __restrict__ outp) {
    __shared__ __align__(16) char smem[16384];
    // stage: Mt 0..5120, Ht 5120..10240 ; row stride 80B

    const int t = threadIdx.x;
    const int lane = t & 63;
    const int wid = t >> 6;
    const int m0 = blockIdx.x * 64;
    const int n0w = wid * 32;

    f32x4 acc[4][2];
    #pragma unroll
    for (int mr = 0; mr < 4; ++mr)
        #pragma unroll
        for (int nr = 0; nr < 2; ++nr) acc[mr][nr] = (f32x4){0.f, 0.f, 0.f, 0.f};

    const int srow = t >> 2;            // 0..63
    const int sk8 = (t & 3) * 8;
    const int arow = lane & 15;
    const int kg = (lane >> 4) * 8;     // element offset within 32-k chunk

    uint4 pfM, pfH;
    auto issueA = [&](int kc) {
        int gr = m0 + srow; if (gr >= NN) gr = NN - 1;
        size_t ga = (size_t)gr * FF + kc * 32 + sk8;
        pfM = *(const uint4*)(mb + ga);
        pfH = *(const uint4*)(hb + ga);
    };

    issueA(0);
    for (int kc = 0; kc < 4; ++kc) {
        __syncthreads();
        *(uint4*)(smem +        srow * 80 + sk8 * 2) = pfM;
        *(uint4*)(smem + 5120 + srow * 80 + sk8 * 2) = pfH;
        if (kc < 3) issueA(kc + 1);
        __syncthreads();

        // W fragments direct from global (L2-resident, broadcast across blocks)
        bf16x8 wfrag[4];
        #pragma unroll
        for (int nr = 0; nr < 2; ++nr) {
            int n = n0w + nr * 16 + arow;
            wfrag[nr * 2 + 0] = *(const bf16x8*)(w2 + (size_t)n * FF + kc * 32 + kg);
            wfrag[nr * 2 + 1] = *(const bf16x8*)(w2 + (size_t)(128 + n) * FF + kc * 32 + kg);
        }
        const int kg2 = (lane >> 4) * 16;   // byte offset of 8 bf16
        #pragma unroll
        for (int mr = 0; mr < 4; ++mr) {
            int row = mr * 16 + arow;
            bf16x8 a_m = *(const bf16x8*)(smem +        row * 80 + kg2);
            bf16x8 a_h = *(const bf16x8*)(smem + 5120 + row * 80 + kg2);
            #pragma unroll
            for (int nr = 0; nr < 2; ++nr) {
                acc[mr][nr] = __builtin_amdgcn_mfma_f32_16x16x32_bf16(wfrag[nr * 2 + 0], a_m, acc[mr][nr], 0, 0, 0);
                acc[mr][nr] = __builtin_amdgcn_mfma_f32_16x16x32_bf16(wfrag[nr * 2 + 1], a_h, acc[mr][nr], 0, 0, 0);
            }
        }
    }

    // ---- epilogue via swizzled LDS C-tile ----
    const int nodeL = lane & 15;
    const int rg4 = (lane >> 4) * 4;
    if (WMODE == 0) {
        __syncthreads();
        #pragma unroll
        for (int nr = 0; nr < 2; ++nr) {
            int n = n0w + nr * 16 + rg4;
            float4 bias = *(const float4*)(bl + n);
            int g = n >> 2;
            #pragma unroll
            for (int mr = 0; mr < 4; ++mr) {
                int row = mr * 16 + nodeL;             // 0..63
                f32x4 a = acc[mr][nr];
                float o0 = fmaxf(a[0] + bias.x, 0.f), o1 = fmaxf(a[1] + bias.y, 0.f);
                float o2 = fmaxf(a[2] + bias.z, 0.f), o3 = fmaxf(a[3] + bias.w, 0.f);
                ushort4 p = make_ushort4(f2bf(o0), f2bf(o1), f2bf(o2), f2bf(o3));
                *(ushort4*)(smem + row * 256 + ((g ^ ((row & 7) << 2)) << 3)) = p;
            }
        }
        __syncthreads();
        unsigned short* hout = (unsigned short*)outp;
        #pragma unroll
        for (int it = 0; it < 8; ++it) {
            int idx = t + it * 256;
            int row = idx >> 5;                        // 0..63
            int g = idx & 31;
            int node = m0 + row;
            if (node < NN) {
                ushort4 v = *(const ushort4*)(smem + row * 256 + ((g ^ ((row & 7) << 2)) << 3));
                *(ushort4*)(hout + (size_t)node * FF + g * 4) = v;
            }
        }
    } else {
        float* fout = (float*)outp;
        #pragma unroll
        for (int r = 0; r < 2; ++r) {
            __syncthreads();
            #pragma unroll
            for (int nr = 0; nr < 2; ++nr) {
                int n = n0w + nr * 16 + rg4;
                float4 bias = *(const float4*)(bl + n);
                int g = n >> 2;
                #pragma unroll
                for (int mr = 2 * r; mr < 2 * r + 2; ++mr) {
                    int lrow = mr * 16 + nodeL - 32 * r;   // 0..31
                    f32x4 a = acc[mr][nr];
                    float4 p = make_float4(a[0] + bias.x, a[1] + bias.y,
                                           a[2] + bias.z, a[3] + bias.w);
                    *(float4*)(smem + lrow * 512 + ((g ^ (lrow & 7)) << 4)) = p;
                }
            }
            __syncthreads();
            #pragma unroll
            for (int it = 0; it < 4; ++it) {
                int idx = t + it * 256;
                int lrow = idx >> 5;                   // 0..31
                int g = idx & 31;
                int node = m0 + 32 * r + lrow;
                if (node < NN) {
                    float4 v = *(const float4*)(smem + lrow * 512 + ((g ^ (lrow & 7)) << 4));
                    *(float4*)(fout + (size_t)node * FF + g * 4) = v;
                }
            }
        }
    }
}

extern "C" void kernel_launch(void* const* d_in, const int* in_sizes, int n_in,
                              void* d_out, int out_size, void* d_ws, size_t ws_size,
                              hipStream_t stream) {
    const float* x   = (const float*)d_in[0];
    const void*  ei  = d_in[1];
    const float* Wl0 = (const float*)d_in[2];
    const float* bl0 = (const float*)d_in[3];
    const float* Wr0 = (const float*)d_in[4];
    const float* Wl1 = (const float*)d_in[5];
    const float* bl1 = (const float*)d_in[6];
    const float* Wr1 = (const float*)d_in[7];
    const float* Wl2 = (const float*)d_in[8];
    const float* bl2 = (const float*)d_in[9];
    const float* Wr2 = (const float*)d_in[10];
    float* out = (float*)d_out;
    const int E = in_sizes[1] / 2;

    char* w = (char*)d_ws;
    size_t off = 0;
    auto alloc = [&](size_t bytes) {
        void* p = w + off;
        off += (bytes + 511) & ~(size_t)511;
        return p;
    };
    int*            flag    = (int*)alloc(4);
    int*            bcnt    = (int*)alloc(sizeof(int) * NB);
    int*            bbase   = (int*)alloc(sizeof(int) * (NB + 1));
    int*            bcursor = (int*)alloc(sizeof(int) * NB);
    int*            rowptr  = (int*)alloc(sizeof(int) * (NN + 1));
    unsigned int*   packed  = (unsigned int*)alloc(sizeof(int) * E);
    int*            col     = (int*)alloc(sizeof(int) * E);
    unsigned short* whi     = (unsigned short*)alloc(sizeof(short) * 3 * 256 * FF);
    unsigned short* xb      = (unsigned short*)alloc(sizeof(short) * (size_t)NN * FF);
    unsigned short* mbuf    = (unsigned short*)alloc(sizeof(short) * (size_t)NN * FF);
    unsigned short* hA      = (unsigned short*)alloc(sizeof(short) * (size_t)NN * FF);
    unsigned short* hB      = xb;   // xb dead after layer-0 gemm; reuse

    // ---- CSR build (bucketed) + prep fused into histogram pass ----
    init_kernel<<<1, 512, 0, stream>>>((const unsigned int*)ei, flag, bcnt);
    bcount_prep_kernel<<<1280, 256, 0, stream>>>(ei, flag, bcnt, E,
                                                 x, xb, Wl0, Wr0, Wl1, Wr1, Wl2, Wr2, whi);
    bscan_kernel<<<1, 512, 0, stream>>>(bcnt, bbase, bcursor, rowptr, E);
    int CH = (E + 255) / 256;
    bscatter_kernel<<<256, 256, 0, stream>>>(ei, flag, bcursor, packed, E, CH);
    bfill_kernel<<<NB, 256, 0, stream>>>(packed, bbase, rowptr, col);

    int gb = (NN + 63) / 64;
    int ab = (NN * 64 + 255) / 256;

    // layer 0: m = mean(xb); h1 = relu(m@Wl0 + xb@Wr0 + bl0)
    aggregate_kernel<<<ab, 256, 0, stream>>>(xb, rowptr, col, mbuf);
    gemm_mfma_kernel<0><<<gb, 256, 0, stream>>>(mbuf, xb, whi + 0 * 256 * FF, bl0, hA);
    // layer 1: m = mean(h1); h2 = relu(m@Wl1 + h1@Wr1 + bl1)  (writes hB = xb buffer)
    aggregate_kernel<<<ab, 256, 0, stream>>>(hA, rowptr, col, mbuf);
    gemm_mfma_kernel<0><<<gb, 256, 0, stream>>>(mbuf, hA, whi + 1 * 256 * FF, bl1, hB);
    // layer 2: m = mean(h2); out = m@Wl2 + h2@Wr2 + bl2  (fp32, no relu)
    aggregate_kernel<<<ab, 256, 0, stream>>>(hB, rowptr, col, mbuf);
    gemm_mfma_kernel<1><<<gb, 256, 0, stream>>>(mbuf, hB, whi + 2 * 256 * FF, bl2, out);
}